// Round 8
// baseline (281.305 us; speedup 1.0000x reference)
//
#include <hip/hip_runtime.h>

#define NC 19
#define NB 10
#define NCELL (NC * NB)            // 190
#define NPART (3 * NCELL + 2 * NC) // 608: conf[190] pred[190] acc[190] psum[19] inval[19]
#define REP 4
#define NSLOT 32                   // global accumulator replicas
#define TPB 256
#define TILE 512                   // pixels per tile -> 2 KB contiguous per class row
#define NROWS (NC + 1)             // 19 class rows + 1 target row
#define BLOCKS 1024                // 4096 tiles / 1024 = 4 contiguous tiles per block

// global -> LDS direct (16B/lane => 1KB per instruction per wave).
__device__ __forceinline__ void load16_lds(const void* g, void* l) {
    auto* gp = reinterpret_cast<const unsigned int __attribute__((address_space(1)))*>(
        reinterpret_cast<uintptr_t>(g));
    auto* lp = reinterpret_cast<unsigned int __attribute__((address_space(3)))*>(
        reinterpret_cast<uintptr_t>(l));
    __builtin_amdgcn_global_load_lds(gp, lp, 16, 0, 0);
}

// ---------------------------------------------------------------------------
// Pass 1: DRAM-row-locality-restoring staged softmax + binned accumulation.
// The r1-r7 plateau (~740 GB/s = 1/8 peak) came from the aggregate address
// stream: all waves concurrently read 19-20 planes exactly 8 MiB apart in
// 128B-1KB fragments -> DRAM row/bank thrash. Here each block stages 2 KB
// CONTIGUOUS per class per tile (TILE=512), and owns 4 consecutive tiles
// (8 KB sequential per class) -> long per-stream runs at the controllers.
// Single 40KB buffer; 3 blocks/CU interleave to cover stage latency.
// Bin-0 (~87% of entries) recovered in pass2 by subtraction:
//   pred(c,0) = valid(c) - sum_{b>=1} pred(c,b)
//   conf(c,0) = psum(c)  - sum_{b>=1} conf(c,b)
// ---------------------------------------------------------------------------
__global__ __launch_bounds__(TPB) void cce_pass1(
    const float* __restrict__ logits, const int* __restrict__ tgt,
    float* __restrict__ gacc, int hw)
{
    constexpr int O_CONF = 0;
    constexpr int O_PRED = REP * NCELL;                // 760
    constexpr int O_ACC  = 2 * REP * NCELL;            // 1520
    constexpr int O_PSUM = 3 * REP * NCELL;            // 2280
    constexpr int O_INV  = O_PSUM + REP * NC;          // 2356
    constexpr int LDS_N  = O_INV + NC;                 // 2375 floats = 9.5 KB

    __shared__ float buf[NROWS][TILE];                 // 40 KB
    __shared__ float hist[LDS_N];                      // 9.5 KB

    for (int i = threadIdx.x; i < LDS_N; i += TPB) hist[i] = 0.0f;
    __syncthreads();

    const int lane = threadIdx.x & 63;
    const int wv   = threadIdx.x >> 6;                 // 0..3
    const int rep  = threadIdx.x & (REP - 1);

    float psum[NC];
#pragma unroll
    for (int c = 0; c < NC; ++c) psum[c] = 0.0f;

    const int ntiles = hw / TILE;                      // 4096
    const int nt     = ntiles / (int)gridDim.x;        // 4 (exact)
    const int start  = (int)blockIdx.x * nt;
    const int end    = start + nt;

    for (int t = start; t < end; ++t) {
        // Stage: wave wv loads rows wv*5..wv*5+4; each row = 2KB = 2 insts.
#pragma unroll
        for (int r5 = 0; r5 < 5; ++r5) {
            const int row = wv * 5 + r5;               // wave-uniform 0..19
#pragma unroll
            for (int i = 0; i < 2; ++i) {
                const void* g = (row < NC)
                    ? (const void*)(logits + (size_t)row * hw + (size_t)t * TILE + i * 256 + lane * 4)
                    : (const void*)(tgt + (size_t)t * TILE + i * 256 + lane * 4);
                load16_lds(g, (void*)&buf[row][i * 256]);
            }
        }
        asm volatile("s_waitcnt vmcnt(0)" ::: "memory");
        __builtin_amdgcn_s_barrier();                  // tile fully staged
        asm volatile("" ::: "memory");

#pragma unroll
        for (int pp = 0; pp < 2; ++pp) {
            const int p = threadIdx.x + pp * TPB;      // 2 px per thread

            float x[NC];
#pragma unroll
            for (int c = 0; c < NC; ++c) x[c] = buf[c][p];
            const int tg = ((const int*)&buf[NC][0])[p];

            float m = x[0];
#pragma unroll
            for (int c = 1; c < NC; ++c) m = fmaxf(m, x[c]);
            float s = 0.0f;
#pragma unroll
            for (int c = 0; c < NC; ++c) { x[c] = __expf(x[c] - m); s += x[c]; }
            const float r = __builtin_amdgcn_rcpf(s);

            float pt = 0.0f, pmin = 1.0f;
#pragma unroll
            for (int c = 0; c < NC; ++c) {
                const float pv = x[c] * r;
                psum[c] += pv;
                pt   = (c == tg) ? pv : pt;            // cndmask (c is imm)
                pmin = fminf(pmin, pv);
                int bb = (int)ceilf(pv * 10.0f) - 1;   // p<=0.1 -> bb<=0
                if (bb > 0) {                          // hot: bin >= 1 (~13%)
                    bb = bb > NB - 1 ? NB - 1 : bb;
                    atomicAdd(&hist[O_CONF + rep * NCELL + c * NB + bb], pv);
                    atomicAdd(&hist[O_PRED + rep * NCELL + c * NB + bb], 1.0f);
                }
            }
            if (pt > 0.0f) {                           // no_acc: 1 atomic/px
                int bt = (int)ceilf(pt * 10.0f) - 1;
                bt = bt < 0 ? 0 : (bt > NB - 1 ? NB - 1 : bt);
                atomicAdd(&hist[O_ACC + rep * NCELL + tg * NB + bt], 1.0f);
            }
            if (!(pmin > 0.0f)) {                      // ultra-rare underflow
#pragma unroll
                for (int c = 0; c < NC; ++c)
                    if (!(x[c] * r > 0.0f)) atomicAdd(&hist[O_INV + c], 1.0f);
            }
        }

        asm volatile("" ::: "memory");
        __builtin_amdgcn_s_barrier();                  // buf free for next tile
    }

#pragma unroll
    for (int c = 0; c < NC; ++c)
        atomicAdd(&hist[O_PSUM + rep * NC + c], psum[c]);
    __syncthreads();

    // Reduce replicas; flush block partials to one of NSLOT global slot sets.
    float* slot = gacc + (size_t)(blockIdx.x & (NSLOT - 1)) * NPART;
    for (int j = threadIdx.x; j < NPART; j += TPB) {
        float v = 0.0f;
        if (j < NCELL) {
            for (int rr = 0; rr < REP; ++rr) v += hist[O_CONF + rr * NCELL + j];
        } else if (j < 2 * NCELL) {
            for (int rr = 0; rr < REP; ++rr) v += hist[O_PRED + rr * NCELL + (j - NCELL)];
        } else if (j < 3 * NCELL) {
            for (int rr = 0; rr < REP; ++rr) v += hist[O_ACC + rr * NCELL + (j - 2 * NCELL)];
        } else if (j < 3 * NCELL + NC) {
            for (int rr = 0; rr < REP; ++rr) v += hist[O_PSUM + rr * NC + (j - 3 * NCELL)];
        } else {
            v = hist[O_INV + (j - 3 * NCELL - NC)];
        }
        atomicAdd(&slot[j], v);
    }
}

// ---------------------------------------------------------------------------
// Pass 2: sum NSLOT slots, bin-0 corrections, 190-cell loss (double).
// slot layout: [0,190) conf, [190,380) pred, [380,570) acc, [570,589) psum,
//              [589,608) inval.
// ---------------------------------------------------------------------------
__global__ void cce_pass2(const float* __restrict__ gacc, float* __restrict__ out, int hw)
{
    __shared__ double fin[NPART];
    const int j = threadIdx.x; // blockDim = 640
    if (j < NPART) {
        double v = 0.0;
        for (int s = 0; s < NSLOT; ++s) v += (double)gacc[(size_t)s * NPART + j];
        fin[j] = v;
    }
    __syncthreads();

    if (j < NC) {
        double spred = 0.0, sconf = 0.0;
        for (int b = 1; b < NB; ++b) {
            spred += fin[NCELL + j * NB + b];
            sconf += fin[j * NB + b];
        }
        const double validc = (double)hw - fin[3 * NCELL + NC + j];
        fin[NCELL + j * NB] = validc - spred;             // pred(c,0)
        fin[j * NB]         = fin[3 * NCELL + j] - sconf; // conf(c,0)
    }
    __syncthreads();

    if (j < 64) {
        double tot = 0.0;
        for (int c = j; c < NCELL; c += 64) tot += fin[NCELL + c];
#pragma unroll
        for (int o = 32; o > 0; o >>= 1) tot += __shfl_down(tot, o);
        tot = __shfl(tot, 0);

        double loss = 0.0;
        for (int c = j; c < NCELL; c += 64) {
            const double pred = fin[NCELL + c];
            const double conf = fin[c];
            const double acc  = fin[2 * NCELL + c];
            const double d    = (acc - conf) / (pred + 1e-13);
            loss += d * d * (pred / tot);
        }
#pragma unroll
        for (int o = 32; o > 0; o >>= 1) loss += __shfl_down(loss, o);
        if (j == 0) out[0] = (float)loss;
    }
}

extern "C" void kernel_launch(void* const* d_in, const int* in_sizes, int n_in,
                              void* d_out, int out_size, void* d_ws, size_t ws_size,
                              hipStream_t stream)
{
    const float* logits = (const float*)d_in[0];
    const int*   tgt    = (const int*)d_in[1];
    float*       gacc   = (float*)d_ws;
    const int    hw     = in_sizes[1]; // 1024*2048

    hipMemsetAsync(gacc, 0, (size_t)NSLOT * NPART * sizeof(float), stream);
    cce_pass1<<<BLOCKS, TPB, 0, stream>>>(logits, tgt, gacc, hw);
    cce_pass2<<<1, 640, 0, stream>>>(gacc, (float*)d_out, hw);
}